// Round 3
// baseline (1136.937 us; speedup 1.0000x reference)
//
#include <hip/hip_runtime.h>

// Kuramoto phase dynamics + coherence softmax. B*S=1024 rows, V=50257, 10 steps.
// One 1024-thread block per row. Phase state fully on-chip:
//   p[20]/thread in registers, 30/thread in LDS ([k][tid] thread-private cols).
// Single pass per step: update with previous-step row sums (first-order
// corrected: accumulate predicted post-update sin/cos), so each element is
// touched once per step (2 trans instead of 4, 1 LDS read + 1 write).
// Lag/approx error ~3e-6 in phase; output sensitivity 4e-5/unit-phase ->
// ~1e-10 output error vs 6.6e-7 threshold.

#define V_DIM    50257
#define NROWS    1024
#define NTHREADS 1024
#define NREG     20
#define NLDS     30
#define N_STEPS  10

__device__ __forceinline__ void block_reduce2(float& a, float& b, float* red) {
    #pragma unroll
    for (int off = 32; off > 0; off >>= 1) {
        a += __shfl_xor(a, off, 64);
        b += __shfl_xor(b, off, 64);
    }
    const int wid = threadIdx.x >> 6;   // 16 waves
    if ((threadIdx.x & 63) == 0) { red[wid] = a; red[16 + wid] = b; }
    __syncthreads();
    float ta = 0.f, tb = 0.f;
    #pragma unroll
    for (int i = 0; i < NTHREADS / 64; ++i) { ta += red[i]; tb += red[16 + i]; }
    __syncthreads();
    a = ta; b = tb;
}

__global__ __launch_bounds__(NTHREADS, 4)
void kuramoto_kernel(const float* __restrict__ logits,
                     const float* __restrict__ omega,
                     const float* __restrict__ noise,
                     float* __restrict__ out) {
    __shared__ float pl[NLDS][NTHREADS];   // 120 KiB, thread-private columns
    __shared__ float red[32];

    const int tid = threadIdx.x;
    const size_t base = (size_t)blockIdx.x * V_DIM;
    const float* __restrict__ lg = logits + base;
    const float* __restrict__ nz = noise + base;
    float* __restrict__ op = out + base;

    const float dtc = 0.1f * (0.1f / (float)V_DIM);   // DT * coupling

    // ---- init: phases = noise + 0.1*logits; initial row sums of sin/cos ----
    float p[NREG], wr[NREG];
    float ss = 0.f, cc = 0.f;
    #pragma unroll
    for (int k = 0; k < NREG; ++k) {
        const int idx = tid + k * NTHREADS;           // max 20479 < V_DIM
        const float ph = nz[idx] + 0.1f * lg[idx];
        p[k]  = ph;
        wr[k] = 0.1f * omega[idx];
        float s, c; __sincosf(ph, &s, &c);
        ss += s; cc += c;
    }
    #pragma unroll
    for (int k = 0; k < NLDS; ++k) {
        const int idx = tid + (NREG + k) * NTHREADS;
        if (idx < V_DIM) {
            const float ph = nz[idx] + 0.1f * lg[idx];
            pl[k][tid] = ph;
            float s, c; __sincosf(ph, &s, &c);
            ss += s; cc += c;
        }
    }
    block_reduce2(ss, cc, red);
    float S = ss, C = cc;   // row-wide sum(sin), sum(cos) of current phases

    // ---- 10 fused steps: update with (S,C); accumulate post-update sums ----
    for (int st = 0; st < N_STEPS; ++st) {
        float nss = 0.f, ncc = 0.f;
        #pragma unroll
        for (int k = 0; k < NREG; ++k) {
            float s, c; __sincosf(p[k], &s, &c);
            const float d = wr[k] + dtc * (s * C - c * S);
            p[k] += d;
            nss += s + c * d;        // ~= sin(p+d), first order
            ncc += c - s * d;        // ~= cos(p+d)
        }
        #pragma unroll
        for (int k = 0; k < NLDS; ++k) {
            const int idx = tid + (NREG + k) * NTHREADS;
            if (idx < V_DIM) {
                const float ph = pl[k][tid];
                float s, c; __sincosf(ph, &s, &c);
                const float d = 0.1f * omega[idx] + dtc * (s * C - c * S);
                pl[k][tid] = ph + d;
                nss += s + c * d;
                ncc += c - s * d;
            }
        }
        block_reduce2(nss, ncc, red);
        S = nss; C = ncc;
    }

    // ---- mean(phases) ----
    float psum = 0.f, d0 = 0.f;
    #pragma unroll
    for (int k = 0; k < NREG; ++k) psum += p[k];
    #pragma unroll
    for (int k = 0; k < NLDS; ++k) {
        const int idx = tid + (NREG + k) * NTHREADS;
        if (idx < V_DIM) psum += pl[k][tid];
    }
    block_reduce2(psum, d0, red);
    const float mean = psum / (float)V_DIM;

    // ---- e = exp(cos(p - mean)); store e in place; reduce sum ----
    float esum = 0.f, d1 = 0.f;
    #pragma unroll
    for (int k = 0; k < NREG; ++k) {
        const float e = __expf(__cosf(p[k] - mean));
        p[k] = e;
        esum += e;
    }
    #pragma unroll
    for (int k = 0; k < NLDS; ++k) {
        const int idx = tid + (NREG + k) * NTHREADS;
        if (idx < V_DIM) {
            const float e = __expf(__cosf(pl[k][tid] - mean));
            pl[k][tid] = e;
            esum += e;
        }
    }
    block_reduce2(esum, d1, red);
    const float inv = 1.f / esum;

    #pragma unroll
    for (int k = 0; k < NREG; ++k) {
        op[tid + k * NTHREADS] = p[k] * inv;
    }
    #pragma unroll
    for (int k = 0; k < NLDS; ++k) {
        const int idx = tid + (NREG + k) * NTHREADS;
        if (idx < V_DIM) op[idx] = pl[k][tid] * inv;
    }
}

extern "C" void kernel_launch(void* const* d_in, const int* in_sizes, int n_in,
                              void* d_out, int out_size, void* d_ws, size_t ws_size,
                              hipStream_t stream) {
    const float* logits = (const float*)d_in[0];
    const float* omega  = (const float*)d_in[1];  // natural_frequencies [V]
    const float* noise  = (const float*)d_in[2];
    float* out = (float*)d_out;
    (void)d_ws; (void)ws_size; (void)in_sizes; (void)n_in; (void)out_size;

    kuramoto_kernel<<<NROWS, NTHREADS, 0, stream>>>(logits, omega, noise, out);
}

// Round 4
// 1084.445 us; speedup vs baseline: 1.0484x; 1.0484x over previous
//
#include <hip/hip_runtime.h>

// Kuramoto phase dynamics + coherence softmax. B*S=1024 rows, V=50257, 10 steps.
// One 1024-thread block per row. Phase state fully on-chip, sized for the
// 64-VGPR allocation the compiler insists on (r2/r3 evidence: attrs don't
// raise the cap; p[20]+wr[20] spilled to scratch -> GBs of HBM traffic):
//   - p[12] + wr[12] in registers (24 regs + temps < 64, no spill)
//   - 38 elems/thread in LDS (155.6 KiB, [k][tid] thread-private columns,
//     conflict-free, no barriers needed for private access)
// Single fused pass per step: update with previous-step row sums, accumulate
// first-order-corrected post-update sin/cos (sin(p+d) ~= s + c*d). Phase error
// ~3e-6; output sensitivity ~4e-5/unit-phase -> ~1e-10 error vs 6.6e-7 thresh.

#define V_DIM    50257
#define NROWS    1024
#define NTHREADS 1024
#define NREG     12
#define NLDS     38
#define N_STEPS  10

__device__ __forceinline__ void block_reduce2(float& a, float& b, float* red) {
    #pragma unroll
    for (int off = 32; off > 0; off >>= 1) {
        a += __shfl_xor(a, off, 64);
        b += __shfl_xor(b, off, 64);
    }
    const int wid = threadIdx.x >> 6;   // 16 waves
    if ((threadIdx.x & 63) == 0) { red[wid] = a; red[16 + wid] = b; }
    __syncthreads();
    float ta = 0.f, tb = 0.f;
    #pragma unroll
    for (int i = 0; i < NTHREADS / 64; ++i) { ta += red[i]; tb += red[16 + i]; }
    __syncthreads();
    a = ta; b = tb;
}

__global__ __launch_bounds__(NTHREADS)
void kuramoto_kernel(const float* __restrict__ logits,
                     const float* __restrict__ omega,
                     const float* __restrict__ noise,
                     float* __restrict__ out) {
    __shared__ float pl[NLDS][NTHREADS];   // 155,648 B, thread-private columns
    __shared__ float red[32];

    const int tid = threadIdx.x;
    const size_t base = (size_t)blockIdx.x * V_DIM;
    const float* __restrict__ lg = logits + base;
    const float* __restrict__ nz = noise + base;
    float* __restrict__ op = out + base;

    const float dtc = 0.1f * (0.1f / (float)V_DIM);   // DT * coupling

    // ---- init: phases = noise + 0.1*logits; initial row sums of sin/cos ----
    float p[NREG], wr[NREG];
    float ss = 0.f, cc = 0.f;
    #pragma unroll
    for (int k = 0; k < NREG; ++k) {
        const int idx = tid + k * NTHREADS;           // max 12287 < V_DIM
        const float ph = nz[idx] + 0.1f * lg[idx];
        p[k]  = ph;
        wr[k] = 0.1f * omega[idx];
        float s, c; __sincosf(ph, &s, &c);
        ss += s; cc += c;
    }
    #pragma unroll
    for (int k = 0; k < NLDS; ++k) {
        const int idx = tid + (NREG + k) * NTHREADS;
        if (idx < V_DIM) {
            const float ph = nz[idx] + 0.1f * lg[idx];
            pl[k][tid] = ph;
            float s, c; __sincosf(ph, &s, &c);
            ss += s; cc += c;
        }
    }
    block_reduce2(ss, cc, red);
    float S = ss, C = cc;   // row-wide sum(sin), sum(cos) of current phases

    // ---- 10 fused steps ----
    for (int st = 0; st < N_STEPS; ++st) {
        float nss = 0.f, ncc = 0.f;
        #pragma unroll
        for (int k = 0; k < NREG; ++k) {
            float s, c; __sincosf(p[k], &s, &c);
            const float d = wr[k] + dtc * (s * C - c * S);
            p[k] += d;
            nss += s + c * d;        // ~= sin(p+d)
            ncc += c - s * d;        // ~= cos(p+d)
        }
        #pragma unroll
        for (int k = 0; k < NLDS; ++k) {
            const int idx = tid + (NREG + k) * NTHREADS;
            if (idx < V_DIM) {
                const float ph = pl[k][tid];
                float s, c; __sincosf(ph, &s, &c);
                const float d = 0.1f * omega[idx] + dtc * (s * C - c * S);
                pl[k][tid] = ph + d;
                nss += s + c * d;
                ncc += c - s * d;
            }
        }
        block_reduce2(nss, ncc, red);
        S = nss; C = ncc;
    }

    // ---- mean(phases) ----
    float psum = 0.f, d0 = 0.f;
    #pragma unroll
    for (int k = 0; k < NREG; ++k) psum += p[k];
    #pragma unroll
    for (int k = 0; k < NLDS; ++k) {
        const int idx = tid + (NREG + k) * NTHREADS;
        if (idx < V_DIM) psum += pl[k][tid];
    }
    block_reduce2(psum, d0, red);
    const float mean = psum / (float)V_DIM;

    // ---- e = exp(cos(p - mean)); store e in place; reduce sum ----
    float esum = 0.f, d1 = 0.f;
    #pragma unroll
    for (int k = 0; k < NREG; ++k) {
        const float e = __expf(__cosf(p[k] - mean));
        p[k] = e;
        esum += e;
    }
    #pragma unroll
    for (int k = 0; k < NLDS; ++k) {
        const int idx = tid + (NREG + k) * NTHREADS;
        if (idx < V_DIM) {
            const float e = __expf(__cosf(pl[k][tid] - mean));
            pl[k][tid] = e;
            esum += e;
        }
    }
    block_reduce2(esum, d1, red);
    const float inv = 1.f / esum;

    #pragma unroll
    for (int k = 0; k < NREG; ++k) {
        op[tid + k * NTHREADS] = p[k] * inv;
    }
    #pragma unroll
    for (int k = 0; k < NLDS; ++k) {
        const int idx = tid + (NREG + k) * NTHREADS;
        if (idx < V_DIM) op[idx] = pl[k][tid] * inv;
    }
}

extern "C" void kernel_launch(void* const* d_in, const int* in_sizes, int n_in,
                              void* d_out, int out_size, void* d_ws, size_t ws_size,
                              hipStream_t stream) {
    const float* logits = (const float*)d_in[0];
    const float* omega  = (const float*)d_in[1];  // natural_frequencies [V]
    const float* noise  = (const float*)d_in[2];
    float* out = (float*)d_out;
    (void)d_ws; (void)ws_size; (void)in_sizes; (void)n_in; (void)out_size;

    kuramoto_kernel<<<NROWS, NTHREADS, 0, stream>>>(logits, omega, noise, out);
}